// Round 13
// baseline (231.416 us; speedup 1.0000x reference)
//
#include <hip/hip_runtime.h>
#include <hip/hip_bf16.h>

#define N_NODES 10000
#define N_EDGES 320000
#define D 256

typedef __attribute__((ext_vector_type(8))) _Float16 f16x8;
typedef __attribute__((ext_vector_type(4))) _Float16 f16x4;
typedef __attribute__((ext_vector_type(4))) float f32x4;

__device__ __forceinline__ void async_copy16(const void* g, void* l) {
  __builtin_amdgcn_global_load_lds(
      (const __attribute__((address_space(1))) unsigned int*)g,
      (__attribute__((address_space(3))) unsigned int*)l, 16, 0, 0);
}

// stage ROWS x 32 f16 k-chunk into Bs[ROWS*32] with XOR quad swizzle; WAVES waves cooperate
template<int ROWS, int WAVES>
__device__ __forceinline__ void stage_tile(const _Float16* __restrict__ Wb, int k0, int K,
                                           _Float16* Bs, int wave, int lane) {
  const int sr = lane >> 2, ss = lane & 3;
#pragma unroll
  for (int grp = wave; grp < ROWS / 16; grp += WAVES) {
    int r = grp * 16 + sr;
    int gq = ss ^ ((r >> 1) & 3);
    async_copy16(Wb + (size_t)r * K + k0 + gq * 8, Bs + grp * 512);
  }
}
__device__ __forceinline__ f16x8 read_B(const _Float16* Bs, int r, int quad) {
  return *(const f16x8*)(Bs + r * 32 + (quad ^ ((r >> 1) & 3)) * 8);
}

// stage 256x32 k-chunk from fp32 weights (cvt in regs), same swizzled layout. 512 threads.
__device__ __forceinline__ void stage_W_f32(const float* __restrict__ Wz, int k0,
                                            _Float16* Bs, int t) {
#pragma unroll
  for (int rep = 0; rep < 2; ++rep) {
    int slot = t + rep * 512;          // 1024 slots = 256 rows x 4 quads
    int r = slot >> 2, q = slot & 3;
    int gq = q ^ ((r >> 1) & 3);
    const float* gp = Wz + r * 256 + k0 + gq * 8;
    float4 a = *(const float4*)gp;
    float4 b = *(const float4*)(gp + 4);
    f16x8 h;
    h[0] = (_Float16)a.x; h[1] = (_Float16)a.y; h[2] = (_Float16)a.z; h[3] = (_Float16)a.w;
    h[4] = (_Float16)b.x; h[5] = (_Float16)b.y; h[6] = (_Float16)b.z; h[7] = (_Float16)b.w;
    *(f16x8*)(Bs + r * 32 + q * 8) = h;
  }
}

__device__ __forceinline__ float fast_sigmoid(float x) {
  return __builtin_amdgcn_rcpf(1.f + __expf(-x));
}
__device__ __forceinline__ float fast_tanh(float x) {
  float ax = fabsf(x);
  float e = __expf(-2.f * ax);
  float t = (1.f - e) * __builtin_amdgcn_rcpf(1.f + e);
  return copysignf(t, x);
}

// ---------- fused edge NN v4: + edge-bucket fill + tail weight casts (side work) ----------
// grid (157, 2) x 512 thr. W staged from fp32 with in-register cvt (swizzled LDS layout).
__global__ __launch_bounds__(512) void edge_fused(
    const float* __restrict__ feat, const float* __restrict__ W_rel,
    const float* __restrict__ b_rel, _Float16* __restrict__ Mh,
    const int* __restrict__ dst, const int* __restrict__ src, const int* __restrict__ rel,
    int* __restrict__ cnt, unsigned int* __restrict__ rowoff,
    const float* __restrict__ W_ih, const float* __restrict__ b_ih,
    const float* __restrict__ b_hh, const float* __restrict__ W1,
    const float* __restrict__ W2, const float* __restrict__ W3,
    _Float16* __restrict__ Wg, float* __restrict__ bg,
    _Float16* __restrict__ W1h, _Float16* __restrict__ W2h, _Float16* __restrict__ W3h)
{
  __shared__ _Float16 Hs[64 * 266];              // 34,048 B
  __shared__ alignas(16) _Float16 Bs[256 * 32];  // 16,384 B
  const int t = threadIdx.x;
  const int wave = t >> 6, lane = t & 63;
  const int quad = lane >> 4, lrow = lane & 15;
  const int z = blockIdx.y;
  const int m0 = blockIdx.x * 64;
  const float* Wz = W_rel + z * 65536;
  const float* bb = b_rel + z * 256;
  const int wm = (wave >> 2) * 32;
  const int wn = (wave & 3) * 64;

  // ---- side work (fire-and-forget; consumed by agg/tail dispatches) ----
  {
    const int gtid = (blockIdx.y * gridDim.x + blockIdx.x) * 512 + t;  // 0..160767
#pragma unroll
    for (int rep = 0; rep < 2; ++rep) {
      int e = gtid + rep * 160768;
      if (e < N_EDGES) {
        int v = dst[e];
        int pos = atomicAdd(&cnt[v], 1);
        if (pos < 128)   // capacity guard; P(deg>128) ~ 1e-40 at E/N=32
          rowoff[(v << 7) + pos] = (unsigned int)((rel[e] * N_NODES + src[e]) * D);
      }
      int i = gtid + rep * 160768;
      if (i < 279296) {  // tail weight casts: Wg(196608)+W1(32768)+W2(16384)+W3(32768)+bg(768)
        if (i < 196608) {
          // packed row p = 48t + 16*phase + u -> W_ih row (16t+u) + {0,512,768}[phase]
          int p = i >> 8, k = i & 255;
          int tg = p / 48, rem = p - tg * 48;
          int phase = rem >> 4, u = rem & 15;
          int orig = tg * 16 + u + (phase == 1 ? 512 : (phase == 2 ? 768 : 0));
          Wg[i] = (_Float16)W_ih[orig * 256 + k];
        } else {
          int j = i - 196608;
          if (j < 32768) { W1h[j] = (_Float16)W1[j]; }
          else if ((j -= 32768) < 16384) { W2h[j] = (_Float16)W2[j]; }
          else if ((j -= 16384) < 32768) { W3h[j] = (_Float16)W3[j]; }
          else {
            int b = j - 32768;   // 0..767
            int tg = b / 48, rem = b - tg * 48;
            int phase = rem >> 4, u = rem & 15;
            int orig = tg * 16 + u + (phase == 1 ? 512 : (phase == 2 ? 768 : 0));
            bg[b] = b_ih[orig] + b_hh[orig];
          }
        }
      }
    }
  }

  int ar0 = m0 + wm + lrow;      if (ar0 > N_NODES - 1) ar0 = N_NODES - 1;
  int ar1 = m0 + wm + 16 + lrow; if (ar1 > N_NODES - 1) ar1 = N_NODES - 1;
  const float* fr0 = feat + (size_t)ar0 * 256;
  const float* fr1 = feat + (size_t)ar1 * 256;

  f32x4 acc[2][4];
#pragma unroll
  for (int i = 0; i < 2; ++i)
#pragma unroll
    for (int j = 0; j < 4; ++j) acc[i][j] = (f32x4)0.0f;

  // ---- layer 1: A from global fp32 (cvt), W from fp32 (cvt -> swizzled LDS) ----
#pragma unroll
  for (int kc = 0; kc < 8; ++kc) {
    stage_W_f32(Wz, kc * 32, Bs, t);
    float4 u0 = *(const float4*)(fr0 + kc * 32 + quad * 8);
    float4 u1 = *(const float4*)(fr0 + kc * 32 + quad * 8 + 4);
    float4 v0 = *(const float4*)(fr1 + kc * 32 + quad * 8);
    float4 v1 = *(const float4*)(fr1 + kc * 32 + quad * 8 + 4);
    f16x8 af0, af1;
    af0[0] = (_Float16)u0.x; af0[1] = (_Float16)u0.y; af0[2] = (_Float16)u0.z; af0[3] = (_Float16)u0.w;
    af0[4] = (_Float16)u1.x; af0[5] = (_Float16)u1.y; af0[6] = (_Float16)u1.z; af0[7] = (_Float16)u1.w;
    af1[0] = (_Float16)v0.x; af1[1] = (_Float16)v0.y; af1[2] = (_Float16)v0.z; af1[3] = (_Float16)v0.w;
    af1[4] = (_Float16)v1.x; af1[5] = (_Float16)v1.y; af1[6] = (_Float16)v1.z; af1[7] = (_Float16)v1.w;
    __syncthreads();
#pragma unroll
    for (int j = 0; j < 4; ++j) {
      f16x8 bf = read_B(Bs, wn + j * 16 + lrow, quad);
      acc[0][j] = __builtin_amdgcn_mfma_f32_16x16x32_f16(af0, bf, acc[0][j], 0, 0, 0);
      acc[1][j] = __builtin_amdgcn_mfma_f32_16x16x32_f16(af1, bf, acc[1][j], 0, 0, 0);
    }
    __syncthreads();
  }
  // H epilogue -> Hs
#pragma unroll
  for (int i = 0; i < 2; ++i) {
    int rb = wm + i * 16 + quad * 4;
#pragma unroll
    for (int j = 0; j < 4; ++j) {
      int col = wn + j * 16 + lrow;
      float bv = bb[col];
#pragma unroll
      for (int reg = 0; reg < 4; ++reg) {
        Hs[(rb + reg) * 266 + col] = (_Float16)fmaxf(acc[i][j][reg] + bv, 0.f);
        acc[i][j][reg] = 0.f;
      }
    }
  }
  __syncthreads();

  // ---- layer 2 (tied W): A from Hs ----
#pragma unroll
  for (int kc = 0; kc < 8; ++kc) {
    stage_W_f32(Wz, kc * 32, Bs, t);
    f16x8 af0 = *(const f16x8*)(Hs + (wm + lrow) * 266 + kc * 32 + quad * 8);
    f16x8 af1 = *(const f16x8*)(Hs + (wm + 16 + lrow) * 266 + kc * 32 + quad * 8);
    __syncthreads();
#pragma unroll
    for (int j = 0; j < 4; ++j) {
      f16x8 bf = read_B(Bs, wn + j * 16 + lrow, quad);
      acc[0][j] = __builtin_amdgcn_mfma_f32_16x16x32_f16(af0, bf, acc[0][j], 0, 0, 0);
      acc[1][j] = __builtin_amdgcn_mfma_f32_16x16x32_f16(af1, bf, acc[1][j], 0, 0, 0);
    }
    __syncthreads();
  }
  _Float16* Mo = Mh + (size_t)z * (N_NODES * D);
#pragma unroll
  for (int i = 0; i < 2; ++i) {
    int rb = m0 + wm + i * 16 + quad * 4;
#pragma unroll
    for (int j = 0; j < 4; ++j) {
      int col = wn + j * 16 + lrow;
      float bv = bb[col];
#pragma unroll
      for (int reg = 0; reg < 4; ++reg) {
        int gm = rb + reg;
        if (gm < N_NODES)
          Mo[(size_t)gm * D + col] = (_Float16)fmaxf(acc[i][j][reg] + bv, 0.f);
      }
    }
  }
}

// ---------- aggregation (R12, proven): one block per node, padded buckets ----------
__global__ __launch_bounds__(256) void agg_kernel(const int* __restrict__ cnt,
                                                  const unsigned int* __restrict__ rowoff,
                                                  const _Float16* __restrict__ Mh,
                                                  _Float16* __restrict__ aggh) {
  __shared__ float part[4][256];
  const int node = blockIdx.x;
  const int wave = threadIdx.x >> 6, lane = threadIdx.x & 63;
  const int base = node << 7;
  const int deg = cnt[node];
  float a0 = 0.f, a1 = 0.f, a2 = 0.f, a3 = 0.f;
  for (int j = wave; j < deg; j += 4) {
    unsigned int off = rowoff[base + j];
    f16x4 v = *(const f16x4*)(Mh + (size_t)off + lane * 4);
    a0 += (float)v[0]; a1 += (float)v[1]; a2 += (float)v[2]; a3 += (float)v[3];
  }
  *(float4*)&part[wave][lane * 4] = make_float4(a0, a1, a2, a3);
  __syncthreads();
  if (wave == 0) {
    float4 p0 = *(const float4*)&part[0][lane * 4];
    float4 p1 = *(const float4*)&part[1][lane * 4];
    float4 p2 = *(const float4*)&part[2][lane * 4];
    float4 p3 = *(const float4*)&part[3][lane * 4];
    f16x4 o;
    o[0] = (_Float16)(p0.x + p1.x + p2.x + p3.x);
    o[1] = (_Float16)(p0.y + p1.y + p2.y + p3.y);
    o[2] = (_Float16)(p0.z + p1.z + p2.z + p3.z);
    o[3] = (_Float16)(p0.w + p1.w + p2.w + p3.w);
    *(f16x4*)(aggh + (size_t)node * D + lane * 4) = o;
  }
}

// ---------- tail (R12, proven): gates GEMM + LSTM + 3-layer MLP ----------
__global__ __launch_bounds__(256) void tail(
    const _Float16* __restrict__ aggh,
    const _Float16* __restrict__ Wg, const float* __restrict__ bg,
    const _Float16* __restrict__ W1h, const float* __restrict__ b1,
    const _Float16* __restrict__ W2h, const float* __restrict__ b2,
    const _Float16* __restrict__ W3h, const float* __restrict__ b3,
    float* __restrict__ out)
{
  __shared__ alignas(16) _Float16 Ws[768 * 32];  // 49,152 B
  __shared__ _Float16 Hn[16 * 266];
  __shared__ _Float16 Xs[16 * 138];
  __shared__ _Float16 X2s[16 * 138];
  const int t = threadIdx.x;
  const int wave = t >> 6, lane = t & 63;
  const int quad = lane >> 4, lrow = lane & 15;
  const int r0 = blockIdx.x * 16;

  // ---- Phase B: gates + LSTM -> Hn ----
  {
    f16x8 af[8];
#pragma unroll
    for (int kc = 0; kc < 8; ++kc)
      af[kc] = *(const f16x8*)(aggh + (size_t)(r0 + lrow) * 256 + kc * 32 + quad * 8);
    f32x4 acc[12];
#pragma unroll
    for (int j = 0; j < 12; ++j) acc[j] = (f32x4)0.0f;
#pragma unroll
    for (int kc = 0; kc < 8; ++kc) {
      stage_tile<768, 4>(Wg, kc * 32, 256, Ws, wave, lane);
      __syncthreads();
#pragma unroll
      for (int j = 0; j < 12; ++j) {
        f16x8 bf = read_B(Ws, (wave * 12 + j) * 16 + lrow, quad);
        acc[j] = __builtin_amdgcn_mfma_f32_16x16x32_f16(af[kc], bf, acc[j], 0, 0, 0);
      }
      __syncthreads();
    }
#pragma unroll
    for (int p = 0; p < 4; ++p) {
      float bvi = bg[(wave * 12 + 3 * p + 0) * 16 + lrow];
      float bvg = bg[(wave * 12 + 3 * p + 1) * 16 + lrow];
      float bvo = bg[(wave * 12 + 3 * p + 2) * 16 + lrow];
      int dcol = (wave * 4 + p) * 16 + lrow;
#pragma unroll
      for (int reg = 0; reg < 4; ++reg) {
        float vi = acc[3 * p + 0][reg] + bvi;
        float vg = acc[3 * p + 1][reg] + bvg;
        float vo = acc[3 * p + 2][reg] + bvo;
        float c = fast_sigmoid(vi) * fast_tanh(vg);
        Hn[(quad * 4 + reg) * 266 + dcol] = (_Float16)(fast_sigmoid(vo) * fast_tanh(c));
      }
    }
  }
  __syncthreads();

  // ---- Phase C: x1 ----
  {
    f16x8 af[8];
#pragma unroll
    for (int kc = 0; kc < 8; ++kc)
      af[kc] = *(const f16x8*)(Hn + lrow * 266 + kc * 32 + quad * 8);
    f32x4 acc[2];
    acc[0] = (f32x4)0.0f; acc[1] = (f32x4)0.0f;
#pragma unroll
    for (int kc = 0; kc < 8; ++kc) {
      stage_tile<128, 4>(W1h, kc * 32, 256, Ws, wave, lane);
      __syncthreads();
#pragma unroll
      for (int j = 0; j < 2; ++j) {
        f16x8 bf = read_B(Ws, wave * 32 + j * 16 + lrow, quad);
        acc[j] = __builtin_amdgcn_mfma_f32_16x16x32_f16(af[kc], bf, acc[j], 0, 0, 0);
      }
      __syncthreads();
    }
#pragma unroll
    for (int j = 0; j < 2; ++j) {
      int col = wave * 32 + j * 16 + lrow;
      float bv = b1[col];
#pragma unroll
      for (int reg = 0; reg < 4; ++reg)
        Xs[(quad * 4 + reg) * 138 + col] = (_Float16)fmaxf(acc[j][reg] + bv, 0.f);
    }
  }
  __syncthreads();

  // ---- Phase D: x2 ----
  {
    f16x8 af[4];
#pragma unroll
    for (int kc = 0; kc < 4; ++kc)
      af[kc] = *(const f16x8*)(Xs + lrow * 138 + kc * 32 + quad * 8);
    f32x4 acc[2];
    acc[0] = (f32x4)0.0f; acc[1] = (f32x4)0.0f;
#pragma unroll
    for (int kc = 0; kc < 4; ++kc) {
      stage_tile<128, 4>(W2h, kc * 32, 128, Ws, wave, lane);
      __syncthreads();
#pragma unroll
      for (int j = 0; j < 2; ++j) {
        f16x8 bf = read_B(Ws, wave * 32 + j * 16 + lrow, quad);
        acc[j] = __builtin_amdgcn_mfma_f32_16x16x32_f16(af[kc], bf, acc[j], 0, 0, 0);
      }
      __syncthreads();
    }
#pragma unroll
    for (int j = 0; j < 2; ++j) {
      int col = wave * 32 + j * 16 + lrow;
      float bv = b2[col];
#pragma unroll
      for (int reg = 0; reg < 4; ++reg)
        X2s[(quad * 4 + reg) * 138 + col] = (_Float16)fmaxf(acc[j][reg] + bv, 0.f);
    }
  }
  __syncthreads();

  // ---- Phase E: out ----
  {
    f16x8 af[4];
#pragma unroll
    for (int kc = 0; kc < 4; ++kc)
      af[kc] = *(const f16x8*)(X2s + lrow * 138 + kc * 32 + quad * 8);
    f32x4 acc[4];
#pragma unroll
    for (int j = 0; j < 4; ++j) acc[j] = (f32x4)0.0f;
#pragma unroll
    for (int kc = 0; kc < 4; ++kc) {
      stage_tile<256, 4>(W3h, kc * 32, 128, Ws, wave, lane);
      __syncthreads();
#pragma unroll
      for (int j = 0; j < 4; ++j) {
        f16x8 bf = read_B(Ws, wave * 64 + j * 16 + lrow, quad);
        acc[j] = __builtin_amdgcn_mfma_f32_16x16x32_f16(af[kc], bf, acc[j], 0, 0, 0);
      }
      __syncthreads();
    }
#pragma unroll
    for (int j = 0; j < 4; ++j) {
      int col = wave * 64 + j * 16 + lrow;
      float bv = b3[col];
#pragma unroll
      for (int reg = 0; reg < 4; ++reg)
        out[(size_t)(r0 + quad * 4 + reg) * 256 + col] = acc[j][reg] + bv;
    }
  }
}

// ---------- launch ----------
extern "C" void kernel_launch(void* const* d_in, const int* in_sizes, int n_in,
                              void* d_out, int out_size, void* d_ws, size_t ws_size,
                              hipStream_t stream) {
  const float* feat  = (const float*)d_in[0];
  const int* src = (const int*)d_in[1];
  const int* dst = (const int*)d_in[2];
  const int* rel = (const int*)d_in[3];
  const float* W_rel = (const float*)d_in[4];
  const float* b_rel = (const float*)d_in[5];
  const float* W_ih  = (const float*)d_in[6];
  const float* b_ih  = (const float*)d_in[7];
  const float* b_hh  = (const float*)d_in[8];
  const float* W1 = (const float*)d_in[9];
  const float* b1 = (const float*)d_in[10];
  const float* W2 = (const float*)d_in[11];
  const float* b2 = (const float*)d_in[12];
  const float* W3 = (const float*)d_in[13];
  const float* b3 = (const float*)d_in[14];
  float* out = (float*)d_out;

  char* ws = (char*)d_ws;
  _Float16* Mh   = (_Float16*)(ws);              // 10,240,000 B (2 rel slabs)
  _Float16* aggh = (_Float16*)(ws + 10240000);   //  5,120,000
  char* wsb = ws + 15360000;
  _Float16* Wg  = (_Float16*)(wsb);              // 393,216
  _Float16* W1h = (_Float16*)(wsb + 393216);     // 65,536
  _Float16* W2h = (_Float16*)(wsb + 458752);     // 32,768
  _Float16* W3h = (_Float16*)(wsb + 491520);     // 65,536
  float*    bg  = (float*)(wsb + 557056);        // 3,072
  int*      cnt = (int*)(wsb + 560128);          // 40,000
  unsigned int* rowoff = (unsigned int*)(wsb + 600128);  // 5,120,000 (10000*128*4)

  // 1) zero bucket counters
  (void)hipMemsetAsync(cnt, 0, N_NODES * sizeof(int), stream);
  // 2) fused edge NN + edge-bucket fill + tail weight casts
  edge_fused<<<dim3(157, 2), 512, 0, stream>>>(
      feat, W_rel, b_rel, Mh, dst, src, rel, cnt, rowoff,
      W_ih, b_ih, b_hh, W1, W2, W3, Wg, bg, W1h, W2h, W3h);
  // 3) scatter-sum via bucket gather
  agg_kernel<<<N_NODES, 256, 0, stream>>>(cnt, rowoff, Mh, aggh);
  // 4) gates + LSTM + MLP -> out
  tail<<<625, 256, 0, stream>>>(aggh, Wg, bg, W1h, b1, W2h, b2, W3h, b3, out);
}

// Round 14
// 210.778 us; speedup vs baseline: 1.0979x; 1.0979x over previous
//
#include <hip/hip_runtime.h>
#include <hip/hip_bf16.h>

#define N_NODES 10000
#define N_EDGES 320000
#define D 256

typedef __attribute__((ext_vector_type(8))) _Float16 f16x8;
typedef __attribute__((ext_vector_type(4))) _Float16 f16x4;
typedef __attribute__((ext_vector_type(4))) float f32x4;

__device__ __forceinline__ void async_copy16(const void* g, void* l) {
  __builtin_amdgcn_global_load_lds(
      (const __attribute__((address_space(1))) unsigned int*)g,
      (__attribute__((address_space(3))) unsigned int*)l, 16, 0, 0);
}

// stage ROWS x 32 f16 k-chunk into Bs[ROWS*32] with XOR quad swizzle; WAVES waves cooperate
template<int ROWS, int WAVES>
__device__ __forceinline__ void stage_tile(const _Float16* __restrict__ Wb, int k0, int K,
                                           _Float16* Bs, int wave, int lane) {
  const int sr = lane >> 2, ss = lane & 3;
#pragma unroll
  for (int grp = wave; grp < ROWS / 16; grp += WAVES) {
    int r = grp * 16 + sr;
    int gq = ss ^ ((r >> 1) & 3);
    async_copy16(Wb + (size_t)r * K + k0 + gq * 8, Bs + grp * 512);
  }
}
__device__ __forceinline__ f16x8 read_B(const _Float16* Bs, int r, int quad) {
  return *(const f16x8*)(Bs + r * 32 + (quad ^ ((r >> 1) & 3)) * 8);
}

__device__ __forceinline__ float fast_sigmoid(float x) {
  return __builtin_amdgcn_rcpf(1.f + __expf(-x));
}
__device__ __forceinline__ float fast_tanh(float x) {
  float ax = fabsf(x);
  float e = __expf(-2.f * ax);
  float t = (1.f - e) * __builtin_amdgcn_rcpf(1.f + e);
  return copysignf(t, x);
}

// ---------- prep_fill: padded-bucket edge fill + weight casts, one dispatch ----------
// requires cnt zeroed (memset before). rowoff[v*128 + pos] = M-row element offset.
__global__ void prep_fill(const int* __restrict__ dst, const int* __restrict__ src,
                          const int* __restrict__ rel,
                          int* __restrict__ cnt, unsigned int* __restrict__ rowoff,
                          const float* __restrict__ W_rel, const float* __restrict__ W_ih,
                          const float* __restrict__ b_ih, const float* __restrict__ b_hh,
                          const float* __restrict__ W1, const float* __restrict__ W2,
                          const float* __restrict__ W3,
                          _Float16* __restrict__ W_relh, _Float16* __restrict__ Wg,
                          float* __restrict__ bg,
                          _Float16* __restrict__ W1h, _Float16* __restrict__ W2h,
                          _Float16* __restrict__ W3h) {
  int i = blockIdx.x * 256 + threadIdx.x;
  if (i < N_EDGES) {
    int v = dst[i];
    int pos = atomicAdd(&cnt[v], 1);
    if (pos < 128)   // capacity guard; P(deg>128) ~ 1e-40 for E/N=32
      rowoff[(v << 7) + pos] = (unsigned int)((rel[i] * N_NODES + src[i]) * D);
    return;
  }
  i -= N_EDGES;
  if (i < 131072) { W_relh[i] = (_Float16)W_rel[i]; return; }
  i -= 131072;
  if (i < 196608) {
    // packed row p = 48t + 16*phase + u -> W_ih row (16t+u) + {0,512,768}[phase]
    int p = i >> 8, k = i & 255;
    int t = p / 48, rem = p - t * 48;
    int phase = rem >> 4, u = rem & 15;
    int orig = t * 16 + u + (phase == 1 ? 512 : (phase == 2 ? 768 : 0));
    Wg[i] = (_Float16)W_ih[orig * 256 + k]; return;
  }
  i -= 196608;
  if (i < 32768) { W1h[i] = (_Float16)W1[i]; return; }
  i -= 32768;
  if (i < 16384) { W2h[i] = (_Float16)W2[i]; return; }
  i -= 16384;
  if (i < 32768) { W3h[i] = (_Float16)W3[i]; return; }
  i -= 32768;
  if (i < 768) {
    int t = i / 48, rem = i - t * 48;
    int phase = rem >> 4, u = rem & 15;
    int orig = t * 16 + u + (phase == 1 ? 512 : (phase == 2 ? 768 : 0));
    bg[i] = b_ih[orig] + b_hh[orig];
  }
}

// ---------- fused edge NN (R9/R12, proven): 512 threads, LDS-staged f16 W ----------
__global__ __launch_bounds__(512) void edge_fused(
    const float* __restrict__ feat, const _Float16* __restrict__ W_relh,
    const float* __restrict__ b_rel, _Float16* __restrict__ Mh)
{
  __shared__ _Float16 Hs[64 * 266];
  __shared__ alignas(16) _Float16 Bs[256 * 32];
  const int t = threadIdx.x;
  const int wave = t >> 6, lane = t & 63;
  const int quad = lane >> 4, lrow = lane & 15;
  const int z = blockIdx.y;
  const int m0 = blockIdx.x * 64;
  const _Float16* Wb = W_relh + z * 65536;
  const float* bb = b_rel + z * 256;
  const int wm = (wave >> 2) * 32;
  const int wn = (wave & 3) * 64;

  int ar0 = m0 + wm + lrow;      if (ar0 > N_NODES - 1) ar0 = N_NODES - 1;
  int ar1 = m0 + wm + 16 + lrow; if (ar1 > N_NODES - 1) ar1 = N_NODES - 1;
  const float* fr0 = feat + (size_t)ar0 * 256;
  const float* fr1 = feat + (size_t)ar1 * 256;

  f32x4 acc[2][4];
#pragma unroll
  for (int i = 0; i < 2; ++i)
#pragma unroll
    for (int j = 0; j < 4; ++j) acc[i][j] = (f32x4)0.0f;

#pragma unroll
  for (int kc = 0; kc < 8; ++kc) {
    stage_tile<256, 8>(Wb, kc * 32, 256, Bs, wave, lane);
    float4 u0 = *(const float4*)(fr0 + kc * 32 + quad * 8);
    float4 u1 = *(const float4*)(fr0 + kc * 32 + quad * 8 + 4);
    float4 v0 = *(const float4*)(fr1 + kc * 32 + quad * 8);
    float4 v1 = *(const float4*)(fr1 + kc * 32 + quad * 8 + 4);
    f16x8 af0, af1;
    af0[0] = (_Float16)u0.x; af0[1] = (_Float16)u0.y; af0[2] = (_Float16)u0.z; af0[3] = (_Float16)u0.w;
    af0[4] = (_Float16)u1.x; af0[5] = (_Float16)u1.y; af0[6] = (_Float16)u1.z; af0[7] = (_Float16)u1.w;
    af1[0] = (_Float16)v0.x; af1[1] = (_Float16)v0.y; af1[2] = (_Float16)v0.z; af1[3] = (_Float16)v0.w;
    af1[4] = (_Float16)v1.x; af1[5] = (_Float16)v1.y; af1[6] = (_Float16)v1.z; af1[7] = (_Float16)v1.w;
    __syncthreads();
#pragma unroll
    for (int j = 0; j < 4; ++j) {
      f16x8 bf = read_B(Bs, wn + j * 16 + lrow, quad);
      acc[0][j] = __builtin_amdgcn_mfma_f32_16x16x32_f16(af0, bf, acc[0][j], 0, 0, 0);
      acc[1][j] = __builtin_amdgcn_mfma_f32_16x16x32_f16(af1, bf, acc[1][j], 0, 0, 0);
    }
    __syncthreads();
  }
#pragma unroll
  for (int i = 0; i < 2; ++i) {
    int rb = wm + i * 16 + quad * 4;
#pragma unroll
    for (int j = 0; j < 4; ++j) {
      int col = wn + j * 16 + lrow;
      float bv = bb[col];
#pragma unroll
      for (int reg = 0; reg < 4; ++reg) {
        Hs[(rb + reg) * 266 + col] = (_Float16)fmaxf(acc[i][j][reg] + bv, 0.f);
        acc[i][j][reg] = 0.f;
      }
    }
  }
  __syncthreads();

#pragma unroll
  for (int kc = 0; kc < 8; ++kc) {
    stage_tile<256, 8>(Wb, kc * 32, 256, Bs, wave, lane);
    f16x8 af0 = *(const f16x8*)(Hs + (wm + lrow) * 266 + kc * 32 + quad * 8);
    f16x8 af1 = *(const f16x8*)(Hs + (wm + 16 + lrow) * 266 + kc * 32 + quad * 8);
    __syncthreads();
#pragma unroll
    for (int j = 0; j < 4; ++j) {
      f16x8 bf = read_B(Bs, wn + j * 16 + lrow, quad);
      acc[0][j] = __builtin_amdgcn_mfma_f32_16x16x32_f16(af0, bf, acc[0][j], 0, 0, 0);
      acc[1][j] = __builtin_amdgcn_mfma_f32_16x16x32_f16(af1, bf, acc[1][j], 0, 0, 0);
    }
    __syncthreads();
  }
  _Float16* Mo = Mh + (size_t)z * (N_NODES * D);
#pragma unroll
  for (int i = 0; i < 2; ++i) {
    int rb = m0 + wm + i * 16 + quad * 4;
#pragma unroll
    for (int j = 0; j < 4; ++j) {
      int col = wn + j * 16 + lrow;
      float bv = bb[col];
#pragma unroll
      for (int reg = 0; reg < 4; ++reg) {
        int gm = rb + reg;
        if (gm < N_NODES)
          Mo[(size_t)gm * D + col] = (_Float16)fmaxf(acc[i][j][reg] + bv, 0.f);
      }
    }
  }
}

// ---------- aggregation (R12, proven): one block per node, padded buckets ----------
__global__ __launch_bounds__(256) void agg_kernel(const int* __restrict__ cnt,
                                                  const unsigned int* __restrict__ rowoff,
                                                  const _Float16* __restrict__ Mh,
                                                  _Float16* __restrict__ aggh) {
  __shared__ float part[4][256];
  const int node = blockIdx.x;
  const int wave = threadIdx.x >> 6, lane = threadIdx.x & 63;
  const int base = node << 7;
  const int deg = cnt[node];
  float a0 = 0.f, a1 = 0.f, a2 = 0.f, a3 = 0.f;
  for (int j = wave; j < deg; j += 4) {
    unsigned int off = rowoff[base + j];
    f16x4 v = *(const f16x4*)(Mh + (size_t)off + lane * 4);
    a0 += (float)v[0]; a1 += (float)v[1]; a2 += (float)v[2]; a3 += (float)v[3];
  }
  *(float4*)&part[wave][lane * 4] = make_float4(a0, a1, a2, a3);
  __syncthreads();
  if (wave == 0) {
    float4 p0 = *(const float4*)&part[0][lane * 4];
    float4 p1 = *(const float4*)&part[1][lane * 4];
    float4 p2 = *(const float4*)&part[2][lane * 4];
    float4 p3 = *(const float4*)&part[3][lane * 4];
    f16x4 o;
    o[0] = (_Float16)(p0.x + p1.x + p2.x + p3.x);
    o[1] = (_Float16)(p0.y + p1.y + p2.y + p3.y);
    o[2] = (_Float16)(p0.z + p1.z + p2.z + p3.z);
    o[3] = (_Float16)(p0.w + p1.w + p2.w + p3.w);
    *(f16x4*)(aggh + (size_t)node * D + lane * 4) = o;
  }
}

// ---------- tail (R12, proven): gates GEMM + LSTM + 3-layer MLP ----------
__global__ __launch_bounds__(256) void tail(
    const _Float16* __restrict__ aggh,
    const _Float16* __restrict__ Wg, const float* __restrict__ bg,
    const _Float16* __restrict__ W1h, const float* __restrict__ b1,
    const _Float16* __restrict__ W2h, const float* __restrict__ b2,
    const _Float16* __restrict__ W3h, const float* __restrict__ b3,
    float* __restrict__ out)
{
  __shared__ alignas(16) _Float16 Ws[768 * 32];  // 49,152 B
  __shared__ _Float16 Hn[16 * 266];
  __shared__ _Float16 Xs[16 * 138];
  __shared__ _Float16 X2s[16 * 138];
  const int t = threadIdx.x;
  const int wave = t >> 6, lane = t & 63;
  const int quad = lane >> 4, lrow = lane & 15;
  const int r0 = blockIdx.x * 16;

  // ---- Phase B: gates + LSTM -> Hn ----
  {
    f16x8 af[8];
#pragma unroll
    for (int kc = 0; kc < 8; ++kc)
      af[kc] = *(const f16x8*)(aggh + (size_t)(r0 + lrow) * 256 + kc * 32 + quad * 8);
    f32x4 acc[12];
#pragma unroll
    for (int j = 0; j < 12; ++j) acc[j] = (f32x4)0.0f;
#pragma unroll
    for (int kc = 0; kc < 8; ++kc) {
      stage_tile<768, 4>(Wg, kc * 32, 256, Ws, wave, lane);
      __syncthreads();
#pragma unroll
      for (int j = 0; j < 12; ++j) {
        f16x8 bf = read_B(Ws, (wave * 12 + j) * 16 + lrow, quad);
        acc[j] = __builtin_amdgcn_mfma_f32_16x16x32_f16(af[kc], bf, acc[j], 0, 0, 0);
      }
      __syncthreads();
    }
#pragma unroll
    for (int p = 0; p < 4; ++p) {
      float bvi = bg[(wave * 12 + 3 * p + 0) * 16 + lrow];
      float bvg = bg[(wave * 12 + 3 * p + 1) * 16 + lrow];
      float bvo = bg[(wave * 12 + 3 * p + 2) * 16 + lrow];
      int dcol = (wave * 4 + p) * 16 + lrow;
#pragma unroll
      for (int reg = 0; reg < 4; ++reg) {
        float vi = acc[3 * p + 0][reg] + bvi;
        float vg = acc[3 * p + 1][reg] + bvg;
        float vo = acc[3 * p + 2][reg] + bvo;
        float c = fast_sigmoid(vi) * fast_tanh(vg);
        Hn[(quad * 4 + reg) * 266 + dcol] = (_Float16)(fast_sigmoid(vo) * fast_tanh(c));
      }
    }
  }
  __syncthreads();

  // ---- Phase C: x1 ----
  {
    f16x8 af[8];
#pragma unroll
    for (int kc = 0; kc < 8; ++kc)
      af[kc] = *(const f16x8*)(Hn + lrow * 266 + kc * 32 + quad * 8);
    f32x4 acc[2];
    acc[0] = (f32x4)0.0f; acc[1] = (f32x4)0.0f;
#pragma unroll
    for (int kc = 0; kc < 8; ++kc) {
      stage_tile<128, 4>(W1h, kc * 32, 256, Ws, wave, lane);
      __syncthreads();
#pragma unroll
      for (int j = 0; j < 2; ++j) {
        f16x8 bf = read_B(Ws, wave * 32 + j * 16 + lrow, quad);
        acc[j] = __builtin_amdgcn_mfma_f32_16x16x32_f16(af[kc], bf, acc[j], 0, 0, 0);
      }
      __syncthreads();
    }
#pragma unroll
    for (int j = 0; j < 2; ++j) {
      int col = wave * 32 + j * 16 + lrow;
      float bv = b1[col];
#pragma unroll
      for (int reg = 0; reg < 4; ++reg)
        Xs[(quad * 4 + reg) * 138 + col] = (_Float16)fmaxf(acc[j][reg] + bv, 0.f);
    }
  }
  __syncthreads();

  // ---- Phase D: x2 ----
  {
    f16x8 af[4];
#pragma unroll
    for (int kc = 0; kc < 4; ++kc)
      af[kc] = *(const f16x8*)(Xs + lrow * 138 + kc * 32 + quad * 8);
    f32x4 acc[2];
    acc[0] = (f32x4)0.0f; acc[1] = (f32x4)0.0f;
#pragma unroll
    for (int kc = 0; kc < 4; ++kc) {
      stage_tile<128, 4>(W2h, kc * 32, 128, Ws, wave, lane);
      __syncthreads();
#pragma unroll
      for (int j = 0; j < 2; ++j) {
        f16x8 bf = read_B(Ws, wave * 32 + j * 16 + lrow, quad);
        acc[j] = __builtin_amdgcn_mfma_f32_16x16x32_f16(af[kc], bf, acc[j], 0, 0, 0);
      }
      __syncthreads();
    }
#pragma unroll
    for (int j = 0; j < 2; ++j) {
      int col = wave * 32 + j * 16 + lrow;
      float bv = b2[col];
#pragma unroll
      for (int reg = 0; reg < 4; ++reg)
        X2s[(quad * 4 + reg) * 138 + col] = (_Float16)fmaxf(acc[j][reg] + bv, 0.f);
    }
  }
  __syncthreads();

  // ---- Phase E: out ----
  {
    f16x8 af[4];
#pragma unroll
    for (int kc = 0; kc < 4; ++kc)
      af[kc] = *(const f16x8*)(X2s + lrow * 138 + kc * 32 + quad * 8);
    f32x4 acc[4];
#pragma unroll
    for (int j = 0; j < 4; ++j) acc[j] = (f32x4)0.0f;
#pragma unroll
    for (int kc = 0; kc < 4; ++kc) {
      stage_tile<256, 4>(W3h, kc * 32, 128, Ws, wave, lane);
      __syncthreads();
#pragma unroll
      for (int j = 0; j < 4; ++j) {
        f16x8 bf = read_B(Ws, wave * 64 + j * 16 + lrow, quad);
        acc[j] = __builtin_amdgcn_mfma_f32_16x16x32_f16(af[kc], bf, acc[j], 0, 0, 0);
      }
      __syncthreads();
    }
#pragma unroll
    for (int j = 0; j < 4; ++j) {
      int col = wave * 64 + j * 16 + lrow;
      float bv = b3[col];
#pragma unroll
      for (int reg = 0; reg < 4; ++reg)
        out[(size_t)(r0 + quad * 4 + reg) * 256 + col] = acc[j][reg] + bv;
    }
  }
}

// ---------- launch ----------
extern "C" void kernel_launch(void* const* d_in, const int* in_sizes, int n_in,
                              void* d_out, int out_size, void* d_ws, size_t ws_size,
                              hipStream_t stream) {
  const float* feat  = (const float*)d_in[0];
  const int* src = (const int*)d_in[1];
  const int* dst = (const int*)d_in[2];
  const int* rel = (const int*)d_in[3];
  const float* W_rel = (const float*)d_in[4];
  const float* b_rel = (const float*)d_in[5];
  const float* W_ih  = (const float*)d_in[6];
  const float* b_ih  = (const float*)d_in[7];
  const float* b_hh  = (const float*)d_in[8];
  const float* W1 = (const float*)d_in[9];
  const float* b1 = (const float*)d_in[10];
  const float* W2 = (const float*)d_in[11];
  const float* b2 = (const float*)d_in[12];
  const float* W3 = (const float*)d_in[13];
  const float* b3 = (const float*)d_in[14];
  float* out = (float*)d_out;

  char* ws = (char*)d_ws;
  _Float16* Mh   = (_Float16*)(ws);              // 10,240,000 B (2 rel slabs)
  _Float16* aggh = (_Float16*)(ws + 10240000);   //  5,120,000
  char* wsb = ws + 15360000;
  _Float16* W_relh = (_Float16*)(wsb);             // 262,144
  _Float16* Wg     = (_Float16*)(wsb + 262144);    // 393,216
  _Float16* W1h    = (_Float16*)(wsb + 655360);    // 65,536
  _Float16* W2h    = (_Float16*)(wsb + 720896);    // 32,768
  _Float16* W3h    = (_Float16*)(wsb + 753664);    // 65,536
  float*    bg     = (float*)(wsb + 819200);       // 3,072
  int*      cnt    = (int*)(wsb + 822272);         // 40,000
  unsigned int* rowoff = (unsigned int*)(wsb + 862272);  // 5,120,000 (10000*128*4)

  // 1) zero bucket counters
  (void)hipMemsetAsync(cnt, 0, N_NODES * sizeof(int), stream);
  // 2) padded-bucket edge fill + weight casts
  prep_fill<<<2853, 256, 0, stream>>>(dst, src, rel, cnt, rowoff,
                                      W_rel, W_ih, b_ih, b_hh, W1, W2, W3,
                                      W_relh, Wg, bg, W1h, W2h, W3h);
  // 3) fused edge NN (both layers, both relations)
  edge_fused<<<dim3(157, 2), 512, 0, stream>>>(feat, W_relh, b_rel, Mh);
  // 4) scatter-sum via bucket gather
  agg_kernel<<<N_NODES, 256, 0, stream>>>(cnt, rowoff, Mh, aggh);
  // 5) gates + LSTM + MLP -> out
  tail<<<625, 256, 0, stream>>>(aggh, Wg, bg, W1h, b1, W2h, b2, W3h, b3, out);
}